// Round 3
// baseline (649.207 us; speedup 1.0000x reference)
//
#include <hip/hip_runtime.h>

#define NBATCH 32
#define QH 32
#define KVH 8
#define G 4
#define DH 128
#define BS 128
#define NB 512
#define CONST_VAL 10.0f
#define EPS_T 1.1754943508222875e-38f
#define SCALE_F 0.08838834764831845f

// ws layout (floats):
//   partial: NB*KVH*G*DH  = 2,097,152
//   bsum:    NB*KVH*G     = 16,384
//   S:       NBATCH*KVH*G = 1,024
//   den:     NB*KVH*G     = 16,384

__global__ void pa_zero_S(float* S) {
    int i = blockIdx.x * 256 + threadIdx.x;
    if (i < NBATCH * KVH * G) S[i] = 0.f;
}

// quad_perm DPP add: v += lanes swapped by xor-1 then xor-2 -> every lane holds quad sum
__device__ __forceinline__ float dpp_xor1_add(float v) {
    int sw = __builtin_amdgcn_update_dpp(0, __builtin_bit_cast(int, v), 0xB1, 0xF, 0xF, true);
    return v + __builtin_bit_cast(float, sw);
}
__device__ __forceinline__ float dpp_xor2_add(float v) {
    int sw = __builtin_amdgcn_update_dpp(0, __builtin_bit_cast(int, v), 0x4E, 0xF, 0xF, true);
    return v + __builtin_bit_cast(float, sw);
}
__device__ __forceinline__ float quad_sum(float v) {
    return dpp_xor2_add(dpp_xor1_add(v));
}

__global__ __launch_bounds__(256, 7) void pa_pass1(
    const float* __restrict__ query,       // [B, QH, DH]
    const float* __restrict__ key_cache,   // [NCB, BS, KVH, DH]
    const float* __restrict__ value_cache, // [NCB, BS, KVH, DH]
    const float* __restrict__ mapping,     // [NB, B]
    const float* __restrict__ bias,        // [NB, BS]
    const int*   __restrict__ block_list,  // [NB]
    float* __restrict__ partial,           // [NB, KVH, G, DH]
    float* __restrict__ bsum,              // [NB, KVH, G]
    float* __restrict__ S)                 // [B, KVH, G]
{
    const int n  = blockIdx.x;   // 0..NB-1
    const int kh = blockIdx.y;   // 0..KVH-1
    const int t  = threadIdx.x;  // 0..255

    __shared__ __align__(16) float sW[NBATCH];
    __shared__ __align__(16) float sQ[G * 132];    // padded rows, 16B-aligned stride
    __shared__ __align__(16) float sE[G * 132];
    __shared__ __align__(16) float sBs[G];
    // union scratch: K-phase pdot[s][j][g] (s*36 + j*4 + g, 128*36=4608 fl)
    //                V-phase po[(sg*4+g)*132 + d]   (32*132=4224 fl)
    __shared__ __align__(16) float uS[128 * 36];

    if (t < NBATCH) sW[t] = mapping[n * NBATCH + t];
    __syncthreads();

    // ---- build q_n = sum_b w[b] * SCALE * query[b, kh*G+g, :] ----
    {
        int i0 = t, i1 = t + 256;                 // 512 slots = 4g x 128d
        int g0 = i0 >> 7, d0 = i0 & 127;
        int g1 = i1 >> 7, d1 = i1 & 127;
        float qa = 0.f, qb = 0.f;
        for (int b = 0; b < NBATCH; ++b) {
            float w = sW[b];
            if (w != 0.f) {
                const float* qrow = query + ((size_t)b * QH + (size_t)kh * G) * DH;
                qa += w * qrow[g0 * DH + d0];
                qb += w * qrow[g1 * DH + d1];
            }
        }
        sQ[g0 * 132 + d0] = qa * SCALE_F;
        sQ[g1 * 132 + d1] = qb * SCALE_F;
    }
    __syncthreads();

    const int q4 = t & 31;    // d-quad owner: d = q4*4 .. q4*4+3
    const int sg = t >> 5;    // s-group: s = sg*16 .. sg*16+15

    // hoist q fragments: 16 regs
    float4 qf0 = *(const float4*)&sQ[0 * 132 + q4 * 4];
    float4 qf1 = *(const float4*)&sQ[1 * 132 + q4 * 4];
    float4 qf2 = *(const float4*)&sQ[2 * 132 + q4 * 4];
    float4 qf3 = *(const float4*)&sQ[3 * 132 + q4 * 4];

    const int p = block_list[n];
    const float* kbase = key_cache   + (size_t)p * BS * KVH * DH + (size_t)kh * DH;
    const float* vbase = value_cache + (size_t)p * BS * KVH * DH + (size_t)kh * DH;
    const int row_stride = KVH * DH; // 1024 floats between s rows

    // ---- K phase: register dots, quad DPP reduce, partial write ----
    #pragma unroll 4
    for (int i = 0; i < 16; ++i) {
        int s = sg * 16 + i;
        float4 k = *(const float4*)(kbase + (size_t)s * row_stride + q4 * 4);
        float p0 = k.x * qf0.x + k.y * qf0.y + k.z * qf0.z + k.w * qf0.w;
        float p1 = k.x * qf1.x + k.y * qf1.y + k.z * qf1.z + k.w * qf1.w;
        float p2 = k.x * qf2.x + k.y * qf2.y + k.z * qf2.z + k.w * qf2.w;
        float p3 = k.x * qf3.x + k.y * qf3.y + k.z * qf3.z + k.w * qf3.w;
        p0 = quad_sum(p0); p1 = quad_sum(p1); p2 = quad_sum(p2); p3 = quad_sum(p3);
        if ((t & 3) == 0) {
            *(float4*)&uS[s * 36 + (q4 >> 2) * 4] = make_float4(p0, p1, p2, p3);
        }
    }
    __syncthreads();

    // ---- reduce pdot -> sE (exp with bias) ----
    {
        int g = t & 3, sb = t >> 2;   // sb 0..63
        #pragma unroll
        for (int rep = 0; rep < 2; ++rep) {
            int s = sb + rep * 64;
            float acc = 0.f;
            #pragma unroll
            for (int j = 0; j < 8; ++j) acc += uS[s * 36 + j * 4 + g];
            sE[g * 132 + s] = __expf(acc + bias[(size_t)n * BS + s] - CONST_VAL);
        }
    }
    __syncthreads();

    // ---- per-block sums: wave w reduces sE[w][:] ----
    {
        int wave = t >> 6, lane = t & 63;
        float v = sE[wave * 132 + lane] + sE[wave * 132 + lane + 64];
        for (int off = 32; off > 0; off >>= 1) v += __shfl_down(v, off);
        if (lane == 0) sBs[wave] = v;
    }
    __syncthreads();
    if (t < G) {
        float bsv = sBs[t];
        bsum[((size_t)n * KVH + kh) * G + t] = bsv;
        for (int b = 0; b < NBATCH; ++b) {
            float w = sW[b];
            if (w != 0.f) atomicAdd(&S[(b * KVH + kh) * G + t], w * bsv);
        }
    }

    // ---- V phase: register accumulate, no LDS tile ----
    float o00=0.f,o01=0.f,o02=0.f,o03=0.f;
    float o10=0.f,o11=0.f,o12=0.f,o13=0.f;
    float o20=0.f,o21=0.f,o22=0.f,o23=0.f;
    float o30=0.f,o31=0.f,o32=0.f,o33=0.f;
    #pragma unroll 4
    for (int i = 0; i < 16; ++i) {
        int s = sg * 16 + i;
        float4 v = *(const float4*)(vbase + (size_t)s * row_stride + q4 * 4);
        float e0 = sE[0 * 132 + s], e1 = sE[1 * 132 + s];
        float e2 = sE[2 * 132 + s], e3 = sE[3 * 132 + s];
        o00 += e0 * v.x; o01 += e0 * v.y; o02 += e0 * v.z; o03 += e0 * v.w;
        o10 += e1 * v.x; o11 += e1 * v.y; o12 += e1 * v.z; o13 += e1 * v.w;
        o20 += e2 * v.x; o21 += e2 * v.y; o22 += e2 * v.z; o23 += e2 * v.w;
        o30 += e3 * v.x; o31 += e3 * v.y; o32 += e3 * v.z; o33 += e3 * v.w;
    }
    // write per-thread partials to union scratch (pdot reads finished 2 syncs ago)
    *(float4*)&uS[(sg * 4 + 0) * 132 + q4 * 4] = make_float4(o00, o01, o02, o03);
    *(float4*)&uS[(sg * 4 + 1) * 132 + q4 * 4] = make_float4(o10, o11, o12, o13);
    *(float4*)&uS[(sg * 4 + 2) * 132 + q4 * 4] = make_float4(o20, o21, o22, o23);
    *(float4*)&uS[(sg * 4 + 3) * 132 + q4 * 4] = make_float4(o30, o31, o32, o33);
    __syncthreads();

    // ---- final reduce across 8 s-groups + global write ----
    #pragma unroll
    for (int rep = 0; rep < 2; ++rep) {
        int idx = t + rep * 256;          // 0..511
        int g = idx >> 7, d = idx & 127;
        float acc = 0.f;
        #pragma unroll
        for (int sg2 = 0; sg2 < 8; ++sg2) acc += uS[(sg2 * 4 + g) * 132 + d];
        partial[(((size_t)n * KVH + kh) * G + g) * DH + d] = acc;
    }
}

// den[n,kh,g] = max(bsum[n,kh,g], sum_b map[n,b]*S[b,kh,g] + EPS)
__global__ __launch_bounds__(256) void pa_den(
    const float* __restrict__ mapping,  // [NB, B]
    const float* __restrict__ bsum,     // [NB, KVH, G]
    const float* __restrict__ S,        // [B, KVH, G]
    float* __restrict__ den)            // [NB, KVH, G]
{
    int i = blockIdx.x * 256 + threadIdx.x;
    if (i >= NB * KVH * G) return;
    int g  = i & (G - 1);
    int kh = (i / G) & (KVH - 1);
    int n  = i / (G * KVH);
    float gs = 0.f;
    for (int b = 0; b < NBATCH; ++b)
        gs += mapping[n * NBATCH + b] * S[(b * KVH + kh) * G + g];
    gs += EPS_T;
    den[i] = fmaxf(bsum[i], gs);
}

__global__ __launch_bounds__(256) void pa_pass2(
    const float* __restrict__ mapping,  // [NB, B]
    const float* __restrict__ partial,  // [NB, KVH, G, DH]
    const float* __restrict__ den,      // [NB, KVH, G]
    float* __restrict__ out)            // [B, QH, DH]
{
    int b  = blockIdx.x;   // 0..31
    int kh = blockIdx.y;   // 0..7
    int t  = threadIdx.x;  // 0..255
    int g  = t >> 7;       // 0..1  (also handles g+2)
    int d  = t & 127;

    __shared__ float sWc[NB];  // mapping column b
    for (int i = t; i < NB; i += 256) sWc[i] = mapping[i * NBATCH + b];
    __syncthreads();

    float a0 = 0.f, a1 = 0.f;
    for (int n = 0; n < NB; ++n) {
        float w = sWc[n];
        if (w == 0.f) continue;
        int di = (n * KVH + kh) * G;
        size_t pb = (size_t)di * DH;
        a0 += w * partial[pb + (size_t)g * DH + d] / den[di + g];
        a1 += w * partial[pb + (size_t)(g + 2) * DH + d] / den[di + g + 2];
    }
    size_t ob = ((size_t)b * QH + (size_t)kh * G) * DH;
    out[ob + (size_t)g * DH + d]       = a0;
    out[ob + (size_t)(g + 2) * DH + d] = a1;
}

extern "C" void kernel_launch(void* const* d_in, const int* in_sizes, int n_in,
                              void* d_out, int out_size, void* d_ws, size_t ws_size,
                              hipStream_t stream) {
    const float* query       = (const float*)d_in[0];
    const float* key_cache   = (const float*)d_in[1];
    const float* value_cache = (const float*)d_in[2];
    const float* mapping     = (const float*)d_in[3];
    const float* bias        = (const float*)d_in[4];
    const int*   block_list  = (const int*)d_in[5];
    float* out = (float*)d_out;

    float* partial = (float*)d_ws;
    float* bsum    = partial + (size_t)NB * KVH * G * DH;
    float* S       = bsum + (size_t)NB * KVH * G;
    float* den     = S + (size_t)NBATCH * KVH * G;

    pa_zero_S<<<4, 256, 0, stream>>>(S);
    pa_pass1<<<dim3(NB, KVH), 256, 0, stream>>>(
        query, key_cache, value_cache, mapping, bias, block_list, partial, bsum, S);
    pa_den<<<(NB * KVH * G + 255) / 256, 256, 0, stream>>>(mapping, bsum, S, den);
    pa_pass2<<<dim3(NBATCH, KVH), 256, 0, stream>>>(mapping, partial, den, out);
}